// Round 13
// baseline (267.729 us; speedup 1.0000x reference)
//
#include <hip/hip_runtime.h>
#include <hip/hip_bf16.h>

#define CC 64
#define HW 9216
#define IMG 96
#define PW 100                // padded width/height
#define SPLITS 8
#define SPLEN 1152            // 9216 / 8
#define ITERS 18              // 1152 / 64
#define LOG2E 1.44269504f

typedef _Float16 f16;
typedef __attribute__((ext_vector_type(8))) _Float16 f16x8;
typedef __attribute__((ext_vector_type(4))) _Float16 f16x4;
typedef __attribute__((ext_vector_type(4))) float f32x4;

// ---------------- pad x into f16 [64][100*100] image (zero borders of 2)
__global__ __launch_bounds__(256) void prepad_kernel(
    const float* __restrict__ x, f16* __restrict__ xpad)
{
    int i = blockIdx.x * 256 + threadIdx.x;      // 64 * 10000
    if (i >= CC * PW * PW) return;
    int ci = i / (PW * PW), p = i % (PW * PW);
    int r = p / PW, c = p % PW;
    bool inside = (r >= 2 && r < IMG + 2 && c >= 2 && c < IMG + 2);
    float v = inside ? x[ci * HW + (r - 2) * IMG + (c - 2)] : 0.f;
    xpad[i] = (f16)v;
}

// ---------------- FUSED conv: dilated 3x3 (pad=2, dil=2) + 1x1 conv from padded f16 image
// co=1 per block, 4 outputs/thread. 1x1's center tap = middle of the kh=1 row already loaded.
__global__ __launch_bounds__(256) void conv_dil_kernel(
    const f16* __restrict__ xpad, const float* __restrict__ dW, const float* __restrict__ db,
    const float* __restrict__ cW, const float* __restrict__ cb,
    f16* __restrict__ yq, f16* __restrict__ kt, f16* __restrict__ vt)
{
    const int co = blockIdx.x / 9, chunk = blockIdx.x % 9;   // grid 64*9
    const int t = threadIdx.x;
    const int m0 = chunk * 1024 + 4 * t;         // multiple of 4, never wraps an image row
    const int h = m0 / IMG, w = m0 % IMG;        // w % 4 == 0
    const int pbase = h * PW + w;
    const float* wco = dW + co * 576;            // block-uniform -> s_load
    const float* cwo = cW + co * CC;

    float a0, a1, a2, a3, v0, v1, v2, v3;
    a0 = a1 = a2 = a3 = db[co];
    v0 = v1 = v2 = v3 = cb[co];
    #pragma unroll 2
    for (int ci = 0; ci < CC; ++ci) {
        const f16* rp0 = xpad + ci * (PW * PW) + pbase;
        const float* wk = wco + ci * 9;
        const float cw = cwo[ci];
        #pragma unroll
        for (int kh = 0; kh < 3; ++kh) {
            const f16* rp = rp0 + kh * (2 * PW);
            f16x4 L0 = *(const f16x4*)(rp);      // padded cols w..w+3 (8B aligned)
            f16x4 L1 = *(const f16x4*)(rp + 4);  //             w+4..w+7
            float e0 = (float)L0.x, e1 = (float)L0.y, e2 = (float)L0.z, e3 = (float)L0.w;
            float e4 = (float)L1.x, e5 = (float)L1.y, e6 = (float)L1.z, e7 = (float)L1.w;
            float w0 = wk[kh * 3 + 0], w1 = wk[kh * 3 + 1], w2 = wk[kh * 3 + 2];
            a0 += w0 * e0 + w1 * e2 + w2 * e4;
            a1 += w0 * e1 + w1 * e3 + w2 * e5;
            a2 += w0 * e2 + w1 * e4 + w2 * e6;
            a3 += w0 * e3 + w1 * e5 + w2 * e7;
            if (kh == 1) {                       // 1x1 conv on center taps
                v0 += cw * e2; v1 += cw * e3; v2 += cw * e4; v3 += cw * e5;
            }
        }
    }
    f16 h0 = (f16)a0, h1 = (f16)a1, h2 = (f16)a2, h3 = (f16)a3;
    *(f16x4*)&yq[co * HW + m0] = (f16x4){h0, h1, h2, h3};   // flat chw (Q layout)
    kt[(m0 + 0) * 64 + co] = h0;                            // K^T[m][c]
    kt[(m0 + 1) * 64 + co] = h1;
    kt[(m0 + 2) * 64 + co] = h2;
    kt[(m0 + 3) * 64 + co] = h3;
    float vs[4] = {v0, v1, v2, v3};
    #pragma unroll
    for (int i = 0; i < 4; ++i) {
        int m = m0 + i;                          // vt[col][row]: V[row=m>>6][col=m&63]
        vt[(m & 63) * HW + co * 144 + (m >> 6)] = (f16)vs[i];
    }
}

// ---------------- MFMA flash attention, S^T scheme, BARRIER-FREE loop:
// K/V fragments read directly from global (L1/L2-resident); LDS only for P + alpha
// (same-wave RAW, in-order). No __syncthreads anywhere in the kernel.
__global__ __launch_bounds__(256, 4) void attn_kernel(
    const f16* __restrict__ kt, const f16* __restrict__ vt, const f16* __restrict__ yq,
    f16* __restrict__ acc_ws, float* __restrict__ m_ws, float* __restrict__ l_ws)
{
    __shared__ f16 sPS[4 * 16 * 72];    // per-wave P [query_local][key_local]
    __shared__ float sAL[4 * 16];       // per-wave alpha[query]

    const int t = threadIdx.x;
    const int L = t & 63, w = t >> 6;
    const int g = L >> 4, c16 = L & 15;
    const int qb = blockIdx.x >> 3, sp = blockIdx.x & 7;
    const int n0 = qb * 64;
    const int mbase = sp * SPLEN;
    f16* psw = (f16*)sPS + w * 16 * 72;

    // Q fragments: Q[row][c] = yq_flat[row*64+c] (raw-reshape semantics); cached all kernel
    f16x8 qa[2];
    #pragma unroll
    for (int kc = 0; kc < 2; ++kc)
        qa[kc] = *(const f16x8*)(yq + (n0 + w * 16 + c16) * 64 + g * 8 + kc * 32);

    float mi = -1e30f;
    float li = 0.f;                     // partial row-sum (this lane's 16 key-columns)
    f32x4 acc[4];
    #pragma unroll
    for (int ct = 0; ct < 4; ++ct) acc[ct] = (f32x4){0.f, 0.f, 0.f, 0.f};

    const f16* ktb = kt + (size_t)mbase * 64;
    const f16* vtb = vt + mbase;

    for (int it = 0; it < ITERS; ++it) {
        const int m0 = it * 64;

        // S^T = K Q^T, K fragments direct from global (dense 16B/lane pattern)
        f32x4 s[4];
        #pragma unroll
        for (int mt = 0; mt < 4; ++mt) {
            f32x4 a0 = (f32x4){0.f, 0.f, 0.f, 0.f};
            #pragma unroll
            for (int kc = 0; kc < 2; ++kc) {
                f16x8 kb = *(const f16x8*)&ktb[(m0 + mt * 16 + c16) * 64 + g * 8 + kc * 32];
                a0 = __builtin_amdgcn_mfma_f32_16x16x32_f16(kb, qa[kc], a0, 0, 0, 0);
            }
            s[mt] = a0;
        }
        // threshold mask to ZERO
        #pragma unroll
        for (int mt = 0; mt < 4; ++mt)
            #pragma unroll
            for (int j = 0; j < 4; ++j)
                s[mt][j] = (fabsf(s[mt][j]) > 0.3f) ? s[mt][j] : 0.f;

        // local max tree + 2 cross-lane reduces (queries replicated over g)
        float x0 = fmaxf(fmaxf(s[0][0], s[0][1]), fmaxf(s[0][2], s[0][3]));
        float x1 = fmaxf(fmaxf(s[1][0], s[1][1]), fmaxf(s[1][2], s[1][3]));
        float x2 = fmaxf(fmaxf(s[2][0], s[2][1]), fmaxf(s[2][2], s[2][3]));
        float x3 = fmaxf(fmaxf(s[3][0], s[3][1]), fmaxf(s[3][2], s[3][3]));
        float mx = fmaxf(fmaxf(x0, x1), fmaxf(x2, x3));
        mx = fmaxf(mx, __shfl_xor(mx, 16, 64));
        mx = fmaxf(mx, __shfl_xor(mx, 32, 64));
        float mnew = fmaxf(mi, mx);
        float nL = mnew * LOG2E;
        float alpha = __builtin_amdgcn_exp2f(mi * LOG2E - nL);
        mi = mnew;

        // p = exp2(s*L2E - nL); partial li (cross-lane deferred to end)
        float p[16];
        #pragma unroll
        for (int mt = 0; mt < 4; ++mt)
            #pragma unroll
            for (int j = 0; j < 4; ++j)
                p[mt * 4 + j] = __builtin_amdgcn_exp2f(fmaf(s[mt][j], LOG2E, -nL));
        float q0 = (p[0] + p[1]) + (p[2] + p[3]);
        float q1 = (p[4] + p[5]) + (p[6] + p[7]);
        float q2 = (p[8] + p[9]) + (p[10] + p[11]);
        float q3 = (p[12] + p[13]) + (p[14] + p[15]);
        li = li * alpha + ((q0 + q1) + (q2 + q3));

        // write P to LDS (A-layout; same-wave RAW is ordered)
        #pragma unroll
        for (int mt = 0; mt < 4; ++mt) {
            unsigned u0 = __builtin_bit_cast(unsigned int,
                __builtin_amdgcn_cvt_pkrtz(p[mt * 4 + 0], p[mt * 4 + 1]));
            unsigned u1 = __builtin_bit_cast(unsigned int,
                __builtin_amdgcn_cvt_pkrtz(p[mt * 4 + 2], p[mt * 4 + 3]));
            uint2 uv; uv.x = u0; uv.y = u1;
            *(uint2*)&psw[c16 * 72 + mt * 16 + 4 * g] = uv;
        }

        // alpha distribution: 1 LDS write + 1 b128 broadcast read (same-wave RAW)
        if (g == 0) sAL[w * 16 + c16] = alpha;
        f32x4 aj = *(const f32x4*)&sAL[w * 16 + 4 * g];   // alphas of queries 4g..4g+3
        #pragma unroll
        for (int ct = 0; ct < 4; ++ct)
            #pragma unroll
            for (int j = 0; j < 4; ++j) acc[ct][j] *= aj[j];

        // PV: A = P from LDS, B = V fragments direct from global
        f16x8 pa[2];
        #pragma unroll
        for (int kc = 0; kc < 2; ++kc)
            pa[kc] = *(const f16x8*)&psw[c16 * 72 + g * 8 + kc * 32];
        #pragma unroll
        for (int ct = 0; ct < 4; ++ct)
            #pragma unroll
            for (int kc = 0; kc < 2; ++kc) {
                f16x8 vb = *(const f16x8*)&vtb[(ct * 16 + c16) * HW + m0 + g * 8 + kc * 32];
                acc[ct] = __builtin_amdgcn_mfma_f32_16x16x32_f16(pa[kc], vb, acc[ct], 0, 0, 0);
            }
    }

    // finish partial row-sum (once)
    float li_tot = li;
    li_tot += __shfl_xor(li_tot, 16, 64);
    li_tot += __shfl_xor(li_tot, 32, 64);

    // write partials (no divide; merge kernel combines splits)
    const int base = blockIdx.x;
    #pragma unroll
    for (int ct = 0; ct < 4; ++ct)
        #pragma unroll
        for (int j = 0; j < 4; ++j)
            acc_ws[base * 4096 + (w * 16 + 4 * g + j) * 64 + ct * 16 + c16] = (f16)acc[ct][j];
    if (g == 0) {
        m_ws[base * 64 + w * 16 + c16] = mi;    // unscaled units
        l_ws[base * 64 + w * 16 + c16] = li_tot;
    }
}

// ---------------- merge splits + residual + transpose; grid 576 (16-row sub-tiles)
__global__ __launch_bounds__(256) void merge_kernel(
    const f16* __restrict__ acc_ws, const float* __restrict__ m_ws, const float* __restrict__ l_ws,
    const float* __restrict__ x, float* __restrict__ out)
{
    __shared__ float wsh[SPLITS * 16];
    __shared__ float att[64 * 17];
    const int qb = blockIdx.x >> 2, sub = blockIdx.x & 3;
    const int r0 = sub * 16;
    const int t = threadIdx.x;
    if (t < 16) {
        int row = r0 + t;
        float ms = -1e30f;
        float mv[SPLITS];
        #pragma unroll
        for (int sp = 0; sp < SPLITS; ++sp) {
            mv[sp] = m_ws[(qb * SPLITS + sp) * 64 + row];
            ms = fmaxf(ms, mv[sp]);
        }
        float Lsum = 0.f, ev[SPLITS];
        #pragma unroll
        for (int sp = 0; sp < SPLITS; ++sp) {
            ev[sp] = __builtin_amdgcn_exp2f((mv[sp] - ms) * LOG2E);
            Lsum += l_ws[(qb * SPLITS + sp) * 64 + row] * ev[sp];
        }
        float inv = 1.f / Lsum;
        #pragma unroll
        for (int sp = 0; sp < SPLITS; ++sp)
            wsh[sp * 16 + t] = ev[sp] * inv;
    }
    __syncthreads();
    for (int i = t; i < 1024; i += 256) {
        int rr = i >> 6, c = i & 63;         // c fast -> coalesced acc_ws reads
        float v = 0.f;
        #pragma unroll
        for (int sp = 0; sp < SPLITS; ++sp)
            v += (float)acc_ws[(qb * SPLITS + sp) * 4096 + (r0 + rr) * 64 + c] * wsh[sp * 16 + rr];
        att[c * 17 + rr] = v;
    }
    __syncthreads();
    const int n0 = qb * 64 + r0;
    for (int i = t; i < 1024; i += 256) {
        int c = i >> 4, r = i & 15;
        int idx = c * HW + n0 + r;
        out[idx] = x[idx] + att[c * 17 + r];
    }
}

extern "C" void kernel_launch(void* const* d_in, const int* in_sizes, int n_in,
                              void* d_out, int out_size, void* d_ws, size_t ws_size,
                              hipStream_t stream)
{
    const float* x  = (const float*)d_in[0];
    const float* dW = (const float*)d_in[1];
    const float* db = (const float*)d_in[2];
    const float* cW = (const float*)d_in[3];
    const float* cb = (const float*)d_in[4];
    float* out = (float*)d_out;

    char* ws = (char*)d_ws;
    f16* kt     = (f16*)(ws);                        // 1,179,648 B
    f16* yq     = (f16*)(ws + 1179648);              // 1,179,648 B
    f16* vt     = (f16*)(ws + 2359296);              // 1,179,648 B
    f16* xpad   = (f16*)(ws + 3538944);              // 1,280,000 B
    f16* acc_ws = (f16*)(ws + 4818944);              // 9,437,184 B
    float* m_ws = (float*)(ws + 14256128);           //   294,912 B
    float* l_ws = (float*)(ws + 14551040);           //   294,912 B
                                                     // total 14,845,952 B

    prepad_kernel<<<dim3((CC * PW * PW + 255) / 256), dim3(256), 0, stream>>>(x, xpad);
    conv_dil_kernel<<<dim3(64 * 9), dim3(256), 0, stream>>>(xpad, dW, db, cW, cb, yq, kt, vt);
    attn_kernel<<<dim3(144 * SPLITS), dim3(256), 0, stream>>>(kt, vt, yq, acc_ws, m_ws, l_ws);
    merge_kernel<<<dim3(576), dim3(256), 0, stream>>>(acc_ws, m_ws, l_ws, x, out);
}

// Round 14
// 159.069 us; speedup vs baseline: 1.6831x; 1.6831x over previous
//
#include <hip/hip_runtime.h>
#include <hip/hip_bf16.h>

#define CC 64
#define HW 9216
#define IMG 96
#define PW 100                // padded width/height
#define SPLITS 8
#define SPLEN 1152            // 9216 / 8
#define ITERS 18              // 1152 / 64
#define LOG2E 1.44269504f

typedef _Float16 f16;
typedef __attribute__((ext_vector_type(8))) _Float16 f16x8;
typedef __attribute__((ext_vector_type(4))) _Float16 f16x4;
typedef __attribute__((ext_vector_type(2))) _Float16 f16x2;
typedef __attribute__((ext_vector_type(4))) float f32x4;

// ---------------- pad x into f16 [64][100*100] image (zero borders of 2)
__global__ __launch_bounds__(256) void prepad_kernel(
    const float* __restrict__ x, f16* __restrict__ xpad)
{
    int i = blockIdx.x * 256 + threadIdx.x;      // 64 * 10000
    if (i >= CC * PW * PW) return;
    int ci = i / (PW * PW), p = i % (PW * PW);
    int r = p / PW, c = p % PW;
    bool inside = (r >= 2 && r < IMG + 2 && c >= 2 && c < IMG + 2);
    float v = inside ? x[ci * HW + (r - 2) * IMG + (c - 2)] : 0.f;
    xpad[i] = (f16)v;
}

// ---------------- FUSED conv: dilated 3x3 (pad=2, dil=2) + 1x1, 2 outputs/thread,
// grid 1152 (4.5 blk/CU) for VMEM latency hiding. Weights block-uniform -> s_load.
__global__ __launch_bounds__(256) void conv_dil_kernel(
    const f16* __restrict__ xpad, const float* __restrict__ dW, const float* __restrict__ db,
    const float* __restrict__ cW, const float* __restrict__ cb,
    f16* __restrict__ yq, f16* __restrict__ kt, f16* __restrict__ vt)
{
    const int co = blockIdx.x / 18, chunk = blockIdx.x % 18;   // grid 64*18
    const int t = threadIdx.x;
    const int m0 = chunk * 512 + 2 * t;          // even, never wraps an image row
    const int h = m0 / IMG, w = m0 % IMG;        // w even
    const int pbase = h * PW + w;
    const float* wco = dW + co * 576;            // block-uniform -> s_load
    const float* cwo = cW + co * CC;

    float a0, a1, v0, v1;
    a0 = a1 = db[co];
    v0 = v1 = cb[co];
    #pragma unroll 2
    for (int ci = 0; ci < CC; ++ci) {
        const f16* rp0 = xpad + ci * (PW * PW) + pbase;
        const float* wk = wco + ci * 9;
        const float cw = cwo[ci];
        #pragma unroll
        for (int kh = 0; kh < 3; ++kh) {
            const f16* rp = rp0 + kh * (2 * PW);
            f16x2 A = *(const f16x2*)(rp);       // padded cols w,   w+1
            f16x2 B = *(const f16x2*)(rp + 2);   //             w+2, w+3
            f16x2 C = *(const f16x2*)(rp + 4);   //             w+4, w+5
            float e0 = (float)A.x, e1 = (float)A.y;
            float e2 = (float)B.x, e3 = (float)B.y;
            float e4 = (float)C.x, e5 = (float)C.y;
            float w0 = wk[kh * 3 + 0], w1 = wk[kh * 3 + 1], w2 = wk[kh * 3 + 2];
            a0 += w0 * e0 + w1 * e2 + w2 * e4;
            a1 += w0 * e1 + w1 * e3 + w2 * e5;
            if (kh == 1) {                       // 1x1 conv on center taps (cols w+2, w+3)
                v0 += cw * e2; v1 += cw * e3;
            }
        }
    }
    f16 h0 = (f16)a0, h1 = (f16)a1;
    *(f16x2*)&yq[co * HW + m0] = (f16x2){h0, h1};   // flat chw (Q layout)
    kt[(m0 + 0) * 64 + co] = h0;                    // K^T[m][c]
    kt[(m0 + 1) * 64 + co] = h1;
    // vt[col][row]: V[row=m>>6][col=m&63]
    vt[((m0 + 0) & 63) * HW + co * 144 + ((m0 + 0) >> 6)] = (f16)v0;
    vt[((m0 + 1) & 63) * HW + co * 144 + ((m0 + 1) >> 6)] = (f16)v1;
}

// ---------------- MFMA flash attention (R11 kernel, proven 58.9 us)
__global__ __launch_bounds__(256, 4) void attn_kernel(
    const f16* __restrict__ kt, const f16* __restrict__ vt, const f16* __restrict__ yq,
    f16* __restrict__ acc_ws, float* __restrict__ m_ws, float* __restrict__ l_ws)
{
    __shared__ f16 sKT[64 * 72];        // [key_local][c], row stride 144 B
    __shared__ f16 sVT[64 * 72];        // [channel][key_local]
    __shared__ f16 sPS[4 * 16 * 72];    // per-wave P [query_local][key_local]
    __shared__ float sAL[4 * 16];       // per-wave alpha[query]

    const int t = threadIdx.x;
    const int L = t & 63, w = t >> 6;
    const int g = L >> 4, c16 = L & 15;
    const int qb = blockIdx.x >> 3, sp = blockIdx.x & 7;
    const int n0 = qb * 64;
    const int mbase = sp * SPLEN;
    f16* psw = (f16*)sPS + w * 16 * 72;

    // Q fragments: Q[row][c] = yq_flat[row*64+c] (raw-reshape semantics)
    f16x8 qa[2];
    #pragma unroll
    for (int kc = 0; kc < 2; ++kc)
        qa[kc] = *(const f16x8*)(yq + (n0 + w * 16 + c16) * 64 + g * 8 + kc * 32);

    float mi = -1e30f;
    float li = 0.f;                     // partial row-sum (this lane's 16 key-columns)
    f32x4 acc[4];
    #pragma unroll
    for (int ct = 0; ct < 4; ++ct) acc[ct] = (f32x4){0.f, 0.f, 0.f, 0.f};

    for (int it = 0; it < ITERS; ++it) {
        const int m0 = mbase + it * 64;
        __syncthreads();
        #pragma unroll
        for (int rep = 0; rep < 2; ++rep) {
            int idx = t + rep * 256;
            int row = idx >> 3, ch = idx & 7;
            *(uint4*)&sKT[row * 72 + ch * 8] = *(const uint4*)&kt[(m0 + row) * 64 + ch * 8];
            *(uint4*)&sVT[row * 72 + ch * 8] = *(const uint4*)&vt[row * HW + m0 + ch * 8];
        }
        __syncthreads();

        // S^T = K Q^T : lane (g,c16) gets s[mt][j] = S[query w*16+c16][key m0+mt*16+4g+j]
        f32x4 s[4];
        #pragma unroll
        for (int mt = 0; mt < 4; ++mt) {
            f32x4 a0 = (f32x4){0.f, 0.f, 0.f, 0.f};
            #pragma unroll
            for (int kc = 0; kc < 2; ++kc) {
                f16x8 kb = *(const f16x8*)&sKT[(mt * 16 + c16) * 72 + g * 8 + kc * 32];
                a0 = __builtin_amdgcn_mfma_f32_16x16x32_f16(kb, qa[kc], a0, 0, 0, 0);
            }
            s[mt] = a0;
        }
        // threshold mask to ZERO
        #pragma unroll
        for (int mt = 0; mt < 4; ++mt)
            #pragma unroll
            for (int j = 0; j < 4; ++j)
                s[mt][j] = (fabsf(s[mt][j]) > 0.3f) ? s[mt][j] : 0.f;

        // local max (balanced tree) + 2 cross-lane reduces
        float x0 = fmaxf(fmaxf(s[0][0], s[0][1]), fmaxf(s[0][2], s[0][3]));
        float x1 = fmaxf(fmaxf(s[1][0], s[1][1]), fmaxf(s[1][2], s[1][3]));
        float x2 = fmaxf(fmaxf(s[2][0], s[2][1]), fmaxf(s[2][2], s[2][3]));
        float x3 = fmaxf(fmaxf(s[3][0], s[3][1]), fmaxf(s[3][2], s[3][3]));
        float mx = fmaxf(fmaxf(x0, x1), fmaxf(x2, x3));
        mx = fmaxf(mx, __shfl_xor(mx, 16, 64));
        mx = fmaxf(mx, __shfl_xor(mx, 32, 64));
        float mnew = fmaxf(mi, mx);
        float nL = mnew * LOG2E;
        float alpha = __builtin_amdgcn_exp2f(mi * LOG2E - nL);
        mi = mnew;

        // p = exp2(s*L2E - nL) via fma; local sum tree (no per-iter cross-lane)
        float p[16];
        #pragma unroll
        for (int mt = 0; mt < 4; ++mt)
            #pragma unroll
            for (int j = 0; j < 4; ++j)
                p[mt * 4 + j] = __builtin_amdgcn_exp2f(fmaf(s[mt][j], LOG2E, -nL));
        float q0 = (p[0] + p[1]) + (p[2] + p[3]);
        float q1 = (p[4] + p[5]) + (p[6] + p[7]);
        float q2 = (p[8] + p[9]) + (p[10] + p[11]);
        float q3 = (p[12] + p[13]) + (p[14] + p[15]);
        li = li * alpha + ((q0 + q1) + (q2 + q3));

        // write P: packed cvt + 4 aligned b64 stores
        #pragma unroll
        for (int mt = 0; mt < 4; ++mt) {
            unsigned u0 = __builtin_bit_cast(unsigned int,
                __builtin_amdgcn_cvt_pkrtz(p[mt * 4 + 0], p[mt * 4 + 1]));
            unsigned u1 = __builtin_bit_cast(unsigned int,
                __builtin_amdgcn_cvt_pkrtz(p[mt * 4 + 2], p[mt * 4 + 3]));
            uint2 uv; uv.x = u0; uv.y = u1;
            *(uint2*)&psw[c16 * 72 + mt * 16 + 4 * g] = uv;
        }

        // alpha distribution: 1 LDS write + 1 b128 broadcast read (same-wave RAW ordered)
        if (g == 0) sAL[w * 16 + c16] = alpha;
        f32x4 aj = *(const f32x4*)&sAL[w * 16 + 4 * g];   // alphas of queries 4g..4g+3
        #pragma unroll
        for (int ct = 0; ct < 4; ++ct)
            #pragma unroll
            for (int j = 0; j < 4; ++j) acc[ct][j] *= aj[j];

        // PV: A = P (A-layout from psw), B = V^T tile
        f16x8 pa[2];
        #pragma unroll
        for (int kc = 0; kc < 2; ++kc)
            pa[kc] = *(const f16x8*)&psw[c16 * 72 + g * 8 + kc * 32];
        #pragma unroll
        for (int ct = 0; ct < 4; ++ct)
            #pragma unroll
            for (int kc = 0; kc < 2; ++kc) {
                f16x8 vb = *(const f16x8*)&sVT[(ct * 16 + c16) * 72 + g * 8 + kc * 32];
                acc[ct] = __builtin_amdgcn_mfma_f32_16x16x32_f16(pa[kc], vb, acc[ct], 0, 0, 0);
            }
    }

    // finish partial row-sum (once, not per iter)
    float li_tot = li;
    li_tot += __shfl_xor(li_tot, 16, 64);
    li_tot += __shfl_xor(li_tot, 32, 64);

    // write partials (no divide; merge kernel combines splits)
    const int base = blockIdx.x;
    #pragma unroll
    for (int ct = 0; ct < 4; ++ct)
        #pragma unroll
        for (int j = 0; j < 4; ++j)
            acc_ws[base * 4096 + (w * 16 + 4 * g + j) * 64 + ct * 16 + c16] = (f16)acc[ct][j];
    if (g == 0) {
        m_ws[base * 64 + w * 16 + c16] = mi;    // unscaled units
        l_ws[base * 64 + w * 16 + c16] = li_tot;
    }
}

// ---------------- merge splits + residual + transpose; grid 576 (16-row sub-tiles)
__global__ __launch_bounds__(256) void merge_kernel(
    const f16* __restrict__ acc_ws, const float* __restrict__ m_ws, const float* __restrict__ l_ws,
    const float* __restrict__ x, float* __restrict__ out)
{
    __shared__ float wsh[SPLITS * 16];
    __shared__ float att[64 * 17];
    const int qb = blockIdx.x >> 2, sub = blockIdx.x & 3;
    const int r0 = sub * 16;
    const int t = threadIdx.x;
    if (t < 16) {
        int row = r0 + t;
        float ms = -1e30f;
        float mv[SPLITS];
        #pragma unroll
        for (int sp = 0; sp < SPLITS; ++sp) {
            mv[sp] = m_ws[(qb * SPLITS + sp) * 64 + row];
            ms = fmaxf(ms, mv[sp]);
        }
        float Lsum = 0.f, ev[SPLITS];
        #pragma unroll
        for (int sp = 0; sp < SPLITS; ++sp) {
            ev[sp] = __builtin_amdgcn_exp2f((mv[sp] - ms) * LOG2E);
            Lsum += l_ws[(qb * SPLITS + sp) * 64 + row] * ev[sp];
        }
        float inv = 1.f / Lsum;
        #pragma unroll
        for (int sp = 0; sp < SPLITS; ++sp)
            wsh[sp * 16 + t] = ev[sp] * inv;
    }
    __syncthreads();
    for (int i = t; i < 1024; i += 256) {
        int rr = i >> 6, c = i & 63;         // c fast -> coalesced acc_ws reads
        float v = 0.f;
        #pragma unroll
        for (int sp = 0; sp < SPLITS; ++sp)
            v += (float)acc_ws[(qb * SPLITS + sp) * 4096 + (r0 + rr) * 64 + c] * wsh[sp * 16 + rr];
        att[c * 17 + rr] = v;
    }
    __syncthreads();
    const int n0 = qb * 64 + r0;
    for (int i = t; i < 1024; i += 256) {
        int c = i >> 4, r = i & 15;
        int idx = c * HW + n0 + r;
        out[idx] = x[idx] + att[c * 17 + r];
    }
}

extern "C" void kernel_launch(void* const* d_in, const int* in_sizes, int n_in,
                              void* d_out, int out_size, void* d_ws, size_t ws_size,
                              hipStream_t stream)
{
    const float* x  = (const float*)d_in[0];
    const float* dW = (const float*)d_in[1];
    const float* db = (const float*)d_in[2];
    const float* cW = (const float*)d_in[3];
    const float* cb = (const float*)d_in[4];
    float* out = (float*)d_out;

    char* ws = (char*)d_ws;
    f16* kt     = (f16*)(ws);                        // 1,179,648 B
    f16* yq     = (f16*)(ws + 1179648);              // 1,179,648 B
    f16* vt     = (f16*)(ws + 2359296);              // 1,179,648 B
    f16* xpad   = (f16*)(ws + 3538944);              // 1,280,000 B
    f16* acc_ws = (f16*)(ws + 4818944);              // 9,437,184 B
    float* m_ws = (float*)(ws + 14256128);           //   294,912 B
    float* l_ws = (float*)(ws + 14551040);           //   294,912 B
                                                     // total 14,845,952 B

    prepad_kernel<<<dim3((CC * PW * PW + 255) / 256), dim3(256), 0, stream>>>(x, xpad);
    conv_dil_kernel<<<dim3(64 * 18), dim3(256), 0, stream>>>(xpad, dW, db, cW, cb, yq, kt, vt);
    attn_kernel<<<dim3(144 * SPLITS), dim3(256), 0, stream>>>(kt, vt, yq, acc_ws, m_ws, l_ws);
    merge_kernel<<<dim3(576), dim3(256), 0, stream>>>(acc_ws, m_ws, l_ws, x, out);
}

// Round 15
// 141.711 us; speedup vs baseline: 1.8893x; 1.1225x over previous
//
#include <hip/hip_runtime.h>
#include <hip/hip_bf16.h>

#define CC 64
#define HW 9216
#define IMG 96
#define SPLITS 8
#define SPLEN 1152            // 9216 / 8
#define ITERS 18              // 1152 / 64
#define LOG2E 1.44269504f

typedef _Float16 f16;
typedef __attribute__((ext_vector_type(8))) _Float16 f16x8;
typedef __attribute__((ext_vector_type(4))) _Float16 f16x4;
typedef __attribute__((ext_vector_type(2))) _Float16 f16x2;
typedef __attribute__((ext_vector_type(4))) float f32x4;

// ---------------- prepad + transpose: xt[p][ci] (p in 100x100 padded image, 64 f16 rows)
__global__ __launch_bounds__(256) void prepad_kernel(
    const float* __restrict__ x, f16* __restrict__ xt)
{
    __shared__ float tile[64][65];
    const int p0 = blockIdx.x * 64;              // grid 157 (157*64 = 10048 >= 10000)
    const int t = threadIdx.x;
    const int pl = t & 63;
    const int p = p0 + pl;
    int r = p / 100, c = p % 100;
    bool interior = (r >= 2) && (r < 98) && (c >= 2) && (c < 98);
    int img = (r - 2) * IMG + (c - 2);
    #pragma unroll
    for (int j = 0; j < 16; ++j) {
        int ci = j * 4 + (t >> 6);
        tile[pl][ci] = interior ? x[ci * HW + img] : 0.f;   // coalesced in p
    }
    __syncthreads();
    const int row16 = t >> 4, chunk = t & 15;
    #pragma unroll
    for (int j = 0; j < 4; ++j) {
        int row = j * 16 + row16;
        int pr = p0 + row;
        if (pr < 10000) {
            f16x4 hv = {(f16)tile[row][chunk * 4 + 0], (f16)tile[row][chunk * 4 + 1],
                        (f16)tile[row][chunk * 4 + 2], (f16)tile[row][chunk * 4 + 3]};
            *(f16x4*)&xt[pr * 64 + chunk * 4] = hv;          // coalesced 128B rows
        }
    }
}

// ---------------- MFMA conv: dilated 3x3 (9-tap GEMM over ci) + fused 1x1 (center tap)
// Block = 64 m x 16 co (grid 576). Wave = 16m strip x 16co. W in LDS as Wl[tap][co][ci].
__global__ __launch_bounds__(256) void conv_mfma_kernel(
    const f16* __restrict__ xt, const float* __restrict__ dW, const float* __restrict__ db,
    const float* __restrict__ cW, const float* __restrict__ cb,
    f16* __restrict__ yq, f16* __restrict__ kt, f16* __restrict__ vt)
{
    __shared__ f16 Wl[9 * 16 * 64];      // [tap][co][ci]  18 KB
    __shared__ f16 cWl[16 * 64];         // [co][ci]        2 KB

    const int b = blockIdx.x;            // 144 m-blocks * 4 co-groups
    const int mblk = b >> 2, cog = b & 3;
    const int co0 = cog * 16;
    const int t = threadIdx.x;

    #pragma unroll 4
    for (int j = 0; j < 36; ++j) {       // Wl[tap*1024 + co*64 + ci] <- dW[(co0+co)*576+ci*9+tap]
        int d = j * 256 + t;
        int tap = d >> 10, rem = d & 1023, co = rem >> 6, ci = rem & 63;
        Wl[d] = (f16)dW[(co0 + co) * 576 + ci * 9 + tap];
    }
    #pragma unroll
    for (int j = 0; j < 4; ++j) {
        int d = j * 256 + t;
        cWl[d] = (f16)cW[(co0 + (d >> 6)) * CC + (d & 63)];
    }
    __syncthreads();

    const int w = t >> 6, L = t & 63, g = L >> 4, c16 = L & 15;
    const int ms = mblk * 64 + w * 16;           // 16-aligned, 96%16==0 -> strip in one image row
    const int h = ms / IMG, wc = ms % IMG;
    const int pb = (h + 2) * 100 + (wc + 2) + c16;   // A row p for this lane's m

    // B-fragments (registers, reused): B[k=g*8+j+kc*32][n=c16]
    f16x8 Bf[9][2], Bv[2];
    #pragma unroll
    for (int tap = 0; tap < 9; ++tap)
        #pragma unroll
        for (int kc = 0; kc < 2; ++kc)
            Bf[tap][kc] = *(const f16x8*)&Wl[(tap * 16 + c16) * 64 + g * 8 + kc * 32];
    #pragma unroll
    for (int kc = 0; kc < 2; ++kc)
        Bv[kc] = *(const f16x8*)&cWl[c16 * 64 + g * 8 + kc * 32];

    f32x4 accY = (f32x4){0.f, 0.f, 0.f, 0.f};
    f32x4 accV = (f32x4){0.f, 0.f, 0.f, 0.f};

    #pragma unroll
    for (int tap = 0; tap < 9; ++tap) {
        int kh = tap / 3, kw = tap % 3;
        int toff = (2 * kh - 2) * 100 + (2 * kw - 2);
        const f16* ap = xt + (pb + toff) * 64;
        f16x8 A0 = *(const f16x8*)(ap + g * 8);          // k chunk 0 (ci 0..31)
        f16x8 A1 = *(const f16x8*)(ap + g * 8 + 32);     // k chunk 1 (ci 32..63)
        accY = __builtin_amdgcn_mfma_f32_16x16x32_f16(A0, Bf[tap][0], accY, 0, 0, 0);
        accY = __builtin_amdgcn_mfma_f32_16x16x32_f16(A1, Bf[tap][1], accY, 0, 0, 0);
        if (tap == 4) {                                  // 1x1 conv rides the center tap
            accV = __builtin_amdgcn_mfma_f32_16x16x32_f16(A0, Bv[0], accV, 0, 0, 0);
            accV = __builtin_amdgcn_mfma_f32_16x16x32_f16(A1, Bv[1], accV, 0, 0, 0);
        }
    }

    // D layout: col = c16 = co_local, row = 4g+j = m_local
    const float dbv = db[co0 + c16], cbv = cb[co0 + c16];
    f16 hy[4];
    #pragma unroll
    for (int j = 0; j < 4; ++j) hy[j] = (f16)(accY[j] + dbv);
    // yq[co][m]: 4 consecutive m -> one 8B store
    *(f16x4*)&yq[(co0 + c16) * HW + ms + 4 * g] = (f16x4){hy[0], hy[1], hy[2], hy[3]};
    #pragma unroll
    for (int j = 0; j < 4; ++j)
        kt[(ms + 4 * g + j) * 64 + co0 + c16] = hy[j];   // K^T[m][c]
    #pragma unroll
    for (int j = 0; j < 4; ++j) {
        int m = ms + 4 * g + j;                          // vt[col=m&63][co*144 + row=m>>6]
        vt[(m & 63) * HW + (co0 + c16) * 144 + (m >> 6)] = (f16)(accV[j] + cbv);
    }
}

// ---------------- MFMA flash attention (R11/R14 kernel, proven 56.6 us)
__global__ __launch_bounds__(256, 4) void attn_kernel(
    const f16* __restrict__ kt, const f16* __restrict__ vt, const f16* __restrict__ yq,
    f16* __restrict__ acc_ws, float* __restrict__ m_ws, float* __restrict__ l_ws)
{
    __shared__ f16 sKT[64 * 72];        // [key_local][c], row stride 144 B
    __shared__ f16 sVT[64 * 72];        // [channel][key_local]
    __shared__ f16 sPS[4 * 16 * 72];    // per-wave P [query_local][key_local]
    __shared__ float sAL[4 * 16];       // per-wave alpha[query]

    const int t = threadIdx.x;
    const int L = t & 63, w = t >> 6;
    const int g = L >> 4, c16 = L & 15;
    const int qb = blockIdx.x >> 3, sp = blockIdx.x & 7;
    const int n0 = qb * 64;
    const int mbase = sp * SPLEN;
    f16* psw = (f16*)sPS + w * 16 * 72;

    // Q fragments: Q[row][c] = yq_flat[row*64+c] (raw-reshape semantics)
    f16x8 qa[2];
    #pragma unroll
    for (int kc = 0; kc < 2; ++kc)
        qa[kc] = *(const f16x8*)(yq + (n0 + w * 16 + c16) * 64 + g * 8 + kc * 32);

    float mi = -1e30f;
    float li = 0.f;                     // partial row-sum (this lane's 16 key-columns)
    f32x4 acc[4];
    #pragma unroll
    for (int ct = 0; ct < 4; ++ct) acc[ct] = (f32x4){0.f, 0.f, 0.f, 0.f};

    for (int it = 0; it < ITERS; ++it) {
        const int m0 = mbase + it * 64;
        __syncthreads();
        #pragma unroll
        for (int rep = 0; rep < 2; ++rep) {
            int idx = t + rep * 256;
            int row = idx >> 3, ch = idx & 7;
            *(uint4*)&sKT[row * 72 + ch * 8] = *(const uint4*)&kt[(m0 + row) * 64 + ch * 8];
            *(uint4*)&sVT[row * 72 + ch * 8] = *(const uint4*)&vt[row * HW + m0 + ch * 8];
        }
        __syncthreads();

        // S^T = K Q^T : lane (g,c16) gets s[mt][j] = S[query w*16+c16][key m0+mt*16+4g+j]
        f32x4 s[4];
        #pragma unroll
        for (int mt = 0; mt < 4; ++mt) {
            f32x4 a0 = (f32x4){0.f, 0.f, 0.f, 0.f};
            #pragma unroll
            for (int kc = 0; kc < 2; ++kc) {
                f16x8 kb = *(const f16x8*)&sKT[(mt * 16 + c16) * 72 + g * 8 + kc * 32];
                a0 = __builtin_amdgcn_mfma_f32_16x16x32_f16(kb, qa[kc], a0, 0, 0, 0);
            }
            s[mt] = a0;
        }
        // threshold mask to ZERO
        #pragma unroll
        for (int mt = 0; mt < 4; ++mt)
            #pragma unroll
            for (int j = 0; j < 4; ++j)
                s[mt][j] = (fabsf(s[mt][j]) > 0.3f) ? s[mt][j] : 0.f;

        // local max (balanced tree) + 2 cross-lane reduces
        float x0 = fmaxf(fmaxf(s[0][0], s[0][1]), fmaxf(s[0][2], s[0][3]));
        float x1 = fmaxf(fmaxf(s[1][0], s[1][1]), fmaxf(s[1][2], s[1][3]));
        float x2 = fmaxf(fmaxf(s[2][0], s[2][1]), fmaxf(s[2][2], s[2][3]));
        float x3 = fmaxf(fmaxf(s[3][0], s[3][1]), fmaxf(s[3][2], s[3][3]));
        float mx = fmaxf(fmaxf(x0, x1), fmaxf(x2, x3));
        mx = fmaxf(mx, __shfl_xor(mx, 16, 64));
        mx = fmaxf(mx, __shfl_xor(mx, 32, 64));
        float mnew = fmaxf(mi, mx);
        float nL = mnew * LOG2E;
        float alpha = __builtin_amdgcn_exp2f(mi * LOG2E - nL);
        mi = mnew;

        // p = exp2(s*L2E - nL) via fma; local sum tree (no per-iter cross-lane)
        float p[16];
        #pragma unroll
        for (int mt = 0; mt < 4; ++mt)
            #pragma unroll
            for (int j = 0; j < 4; ++j)
                p[mt * 4 + j] = __builtin_amdgcn_exp2f(fmaf(s[mt][j], LOG2E, -nL));
        float q0 = (p[0] + p[1]) + (p[2] + p[3]);
        float q1 = (p[4] + p[5]) + (p[6] + p[7]);
        float q2 = (p[8] + p[9]) + (p[10] + p[11]);
        float q3 = (p[12] + p[13]) + (p[14] + p[15]);
        li = li * alpha + ((q0 + q1) + (q2 + q3));

        // write P: packed cvt + 4 aligned b64 stores
        #pragma unroll
        for (int mt = 0; mt < 4; ++mt) {
            unsigned u0 = __builtin_bit_cast(unsigned int,
                __builtin_amdgcn_cvt_pkrtz(p[mt * 4 + 0], p[mt * 4 + 1]));
            unsigned u1 = __builtin_bit_cast(unsigned int,
                __builtin_amdgcn_cvt_pkrtz(p[mt * 4 + 2], p[mt * 4 + 3]));
            uint2 uv; uv.x = u0; uv.y = u1;
            *(uint2*)&psw[c16 * 72 + mt * 16 + 4 * g] = uv;
        }

        // alpha distribution: 1 LDS write + 1 b128 broadcast read (same-wave RAW ordered)
        if (g == 0) sAL[w * 16 + c16] = alpha;
        f32x4 aj = *(const f32x4*)&sAL[w * 16 + 4 * g];   // alphas of queries 4g..4g+3
        #pragma unroll
        for (int ct = 0; ct < 4; ++ct)
            #pragma unroll
            for (int j = 0; j < 4; ++j) acc[ct][j] *= aj[j];

        // PV: A = P (A-layout from psw), B = V^T tile
        f16x8 pa[2];
        #pragma unroll
        for (int kc = 0; kc < 2; ++kc)
            pa[kc] = *(const f16x8*)&psw[c16 * 72 + g * 8 + kc * 32];
        #pragma unroll
        for (int ct = 0; ct < 4; ++ct)
            #pragma unroll
            for (int kc = 0; kc < 2; ++kc) {
                f16x8 vb = *(const f16x8*)&sVT[(ct * 16 + c16) * 72 + g * 8 + kc * 32];
                acc[ct] = __builtin_amdgcn_mfma_f32_16x16x32_f16(pa[kc], vb, acc[ct], 0, 0, 0);
            }
    }

    // finish partial row-sum (once, not per iter)
    float li_tot = li;
    li_tot += __shfl_xor(li_tot, 16, 64);
    li_tot += __shfl_xor(li_tot, 32, 64);

    // write partials (no divide; merge kernel combines splits)
    const int base = blockIdx.x;
    #pragma unroll
    for (int ct = 0; ct < 4; ++ct)
        #pragma unroll
        for (int j = 0; j < 4; ++j)
            acc_ws[base * 4096 + (w * 16 + 4 * g + j) * 64 + ct * 16 + c16] = (f16)acc[ct][j];
    if (g == 0) {
        m_ws[base * 64 + w * 16 + c16] = mi;    // unscaled units
        l_ws[base * 64 + w * 16 + c16] = li_tot;
    }
}

// ---------------- merge splits + residual + transpose; grid 576 (16-row sub-tiles)
__global__ __launch_bounds__(256) void merge_kernel(
    const f16* __restrict__ acc_ws, const float* __restrict__ m_ws, const float* __restrict__ l_ws,
    const float* __restrict__ x, float* __restrict__ out)
{
    __shared__ float wsh[SPLITS * 16];
    __shared__ float att[64 * 17];
    const int qb = blockIdx.x >> 2, sub = blockIdx.x & 3;
    const int r0 = sub * 16;
    const int t = threadIdx.x;
    if (t < 16) {
        int row = r0 + t;
        float ms = -1e30f;
        float mv[SPLITS];
        #pragma unroll
        for (int sp = 0; sp < SPLITS; ++sp) {
            mv[sp] = m_ws[(qb * SPLITS + sp) * 64 + row];
            ms = fmaxf(ms, mv[sp]);
        }
        float Lsum = 0.f, ev[SPLITS];
        #pragma unroll
        for (int sp = 0; sp < SPLITS; ++sp) {
            ev[sp] = __builtin_amdgcn_exp2f((mv[sp] - ms) * LOG2E);
            Lsum += l_ws[(qb * SPLITS + sp) * 64 + row] * ev[sp];
        }
        float inv = 1.f / Lsum;
        #pragma unroll
        for (int sp = 0; sp < SPLITS; ++sp)
            wsh[sp * 16 + t] = ev[sp] * inv;
    }
    __syncthreads();
    for (int i = t; i < 1024; i += 256) {
        int rr = i >> 6, c = i & 63;         // c fast -> coalesced acc_ws reads
        float v = 0.f;
        #pragma unroll
        for (int sp = 0; sp < SPLITS; ++sp)
            v += (float)acc_ws[(qb * SPLITS + sp) * 4096 + (r0 + rr) * 64 + c] * wsh[sp * 16 + rr];
        att[c * 17 + rr] = v;
    }
    __syncthreads();
    const int n0 = qb * 64 + r0;
    for (int i = t; i < 1024; i += 256) {
        int c = i >> 4, r = i & 15;
        int idx = c * HW + n0 + r;
        out[idx] = x[idx] + att[c * 17 + r];
    }
}

extern "C" void kernel_launch(void* const* d_in, const int* in_sizes, int n_in,
                              void* d_out, int out_size, void* d_ws, size_t ws_size,
                              hipStream_t stream)
{
    const float* x  = (const float*)d_in[0];
    const float* dW = (const float*)d_in[1];
    const float* db = (const float*)d_in[2];
    const float* cW = (const float*)d_in[3];
    const float* cb = (const float*)d_in[4];
    float* out = (float*)d_out;

    char* ws = (char*)d_ws;
    f16* kt     = (f16*)(ws);                        // 1,179,648 B
    f16* yq     = (f16*)(ws + 1179648);              // 1,179,648 B
    f16* vt     = (f16*)(ws + 2359296);              // 1,179,648 B
    f16* xt     = (f16*)(ws + 3538944);              // 1,280,000 B (xt[p][ci])
    f16* acc_ws = (f16*)(ws + 4818944);              // 9,437,184 B
    float* m_ws = (float*)(ws + 14256128);           //   294,912 B
    float* l_ws = (float*)(ws + 14551040);           //   294,912 B
                                                     // total 14,845,952 B

    prepad_kernel<<<dim3(157), dim3(256), 0, stream>>>(x, xt);
    conv_mfma_kernel<<<dim3(576), dim3(256), 0, stream>>>(xt, dW, db, cW, cb, yq, kt, vt);
    attn_kernel<<<dim3(144 * SPLITS), dim3(256), 0, stream>>>(kt, vt, yq, acc_ws, m_ws, l_ws);
    merge_kernel<<<dim3(576), dim3(256), 0, stream>>>(acc_ws, m_ws, l_ws, x, out);
}

// Round 16
// 139.631 us; speedup vs baseline: 1.9174x; 1.0149x over previous
//
#include <hip/hip_runtime.h>
#include <hip/hip_bf16.h>

#define CC 64
#define HW 9216
#define IMG 96
#define SPLITS 8
#define SPLEN 1152            // 9216 / 8
#define ITERS 18              // 1152 / 64
#define LOG2E 1.44269504f

typedef _Float16 f16;
typedef __attribute__((ext_vector_type(8))) _Float16 f16x8;
typedef __attribute__((ext_vector_type(4))) _Float16 f16x4;
typedef __attribute__((ext_vector_type(4))) float f32x4;
typedef __attribute__((ext_vector_type(16))) float f32x16;

// ---------------- prepad + transpose: xt[p][ci] (p in 100x100 padded image, 64 f16 rows)
__global__ __launch_bounds__(256) void prepad_kernel(
    const float* __restrict__ x, f16* __restrict__ xt)
{
    __shared__ float tile[64][65];
    const int p0 = blockIdx.x * 64;              // grid 157 (157*64 = 10048 >= 10000)
    const int t = threadIdx.x;
    const int pl = t & 63;
    const int p = p0 + pl;
    int r = p / 100, c = p % 100;
    bool interior = (r >= 2) && (r < 98) && (c >= 2) && (c < 98);
    int img = (r - 2) * IMG + (c - 2);
    #pragma unroll
    for (int j = 0; j < 16; ++j) {
        int ci = j * 4 + (t >> 6);
        tile[pl][ci] = interior ? x[ci * HW + img] : 0.f;   // coalesced in p
    }
    __syncthreads();
    const int row16 = t >> 4, chunk = t & 15;
    #pragma unroll
    for (int j = 0; j < 4; ++j) {
        int row = j * 16 + row16;
        int pr = p0 + row;
        if (pr < 10000) {
            f16x4 hv = {(f16)tile[row][chunk * 4 + 0], (f16)tile[row][chunk * 4 + 1],
                        (f16)tile[row][chunk * 4 + 2], (f16)tile[row][chunk * 4 + 3]};
            *(f16x4*)&xt[pr * 64 + chunk * 4] = hv;          // coalesced 128B rows
        }
    }
}

// ---------------- MFMA conv: dilated 3x3 (9-tap GEMM over ci) + fused 1x1 (center tap)
__global__ __launch_bounds__(256) void conv_mfma_kernel(
    const f16* __restrict__ xt, const float* __restrict__ dW, const float* __restrict__ db,
    const float* __restrict__ cW, const float* __restrict__ cb,
    f16* __restrict__ yq, f16* __restrict__ kt, f16* __restrict__ vt)
{
    __shared__ f16 Wl[9 * 16 * 64];      // [tap][co][ci]  18 KB
    __shared__ f16 cWl[16 * 64];         // [co][ci]        2 KB

    const int b = blockIdx.x;            // 144 m-blocks * 4 co-groups
    const int mblk = b >> 2, cog = b & 3;
    const int co0 = cog * 16;
    const int t = threadIdx.x;

    #pragma unroll 4
    for (int j = 0; j < 36; ++j) {       // Wl[tap*1024 + co*64 + ci] <- dW[(co0+co)*576+ci*9+tap]
        int d = j * 256 + t;
        int tap = d >> 10, rem = d & 1023, co = rem >> 6, ci = rem & 63;
        Wl[d] = (f16)dW[(co0 + co) * 576 + ci * 9 + tap];
    }
    #pragma unroll
    for (int j = 0; j < 4; ++j) {
        int d = j * 256 + t;
        cWl[d] = (f16)cW[(co0 + (d >> 6)) * CC + (d & 63)];
    }
    __syncthreads();

    const int w = t >> 6, L = t & 63, g = L >> 4, c16 = L & 15;
    const int ms = mblk * 64 + w * 16;           // 16-aligned strip within one image row
    const int h = ms / IMG, wc = ms % IMG;
    const int pb = (h + 2) * 100 + (wc + 2) + c16;

    f16x8 Bf[9][2], Bv[2];
    #pragma unroll
    for (int tap = 0; tap < 9; ++tap)
        #pragma unroll
        for (int kc = 0; kc < 2; ++kc)
            Bf[tap][kc] = *(const f16x8*)&Wl[(tap * 16 + c16) * 64 + g * 8 + kc * 32];
    #pragma unroll
    for (int kc = 0; kc < 2; ++kc)
        Bv[kc] = *(const f16x8*)&cWl[c16 * 64 + g * 8 + kc * 32];

    f32x4 accY = (f32x4){0.f, 0.f, 0.f, 0.f};
    f32x4 accV = (f32x4){0.f, 0.f, 0.f, 0.f};

    #pragma unroll
    for (int tap = 0; tap < 9; ++tap) {
        int kh = tap / 3, kw = tap % 3;
        int toff = (2 * kh - 2) * 100 + (2 * kw - 2);
        const f16* ap = xt + (pb + toff) * 64;
        f16x8 A0 = *(const f16x8*)(ap + g * 8);
        f16x8 A1 = *(const f16x8*)(ap + g * 8 + 32);
        accY = __builtin_amdgcn_mfma_f32_16x16x32_f16(A0, Bf[tap][0], accY, 0, 0, 0);
        accY = __builtin_amdgcn_mfma_f32_16x16x32_f16(A1, Bf[tap][1], accY, 0, 0, 0);
        if (tap == 4) {
            accV = __builtin_amdgcn_mfma_f32_16x16x32_f16(A0, Bv[0], accV, 0, 0, 0);
            accV = __builtin_amdgcn_mfma_f32_16x16x32_f16(A1, Bv[1], accV, 0, 0, 0);
        }
    }

    const float dbv = db[co0 + c16], cbv = cb[co0 + c16];
    f16 hy[4];
    #pragma unroll
    for (int j = 0; j < 4; ++j) hy[j] = (f16)(accY[j] + dbv);
    *(f16x4*)&yq[(co0 + c16) * HW + ms + 4 * g] = (f16x4){hy[0], hy[1], hy[2], hy[3]};
    #pragma unroll
    for (int j = 0; j < 4; ++j)
        kt[(ms + 4 * g + j) * 64 + co0 + c16] = hy[j];
    #pragma unroll
    for (int j = 0; j < 4; ++j) {
        int m = ms + 4 * g + j;
        vt[(m & 63) * HW + (co0 + c16) * 144 + (m >> 6)] = (f16)(accV[j] + cbv);
    }
}

// ---------------- MFMA flash attention, 32x32x16 tiles: wave = 32 queries, block = 128 q
// D layout (verified): col=lane&31, row=(reg&3)+8*(reg>>2)+4*(lane>>5)
// A layout: A[m=lane&31][k=(lane>>5)*8+j]; B[k=(lane>>5)*8+j][n=lane&31]
__global__ __launch_bounds__(256, 3) void attn_kernel(
    const f16* __restrict__ kt, const f16* __restrict__ vt, const f16* __restrict__ yq,
    f16* __restrict__ acc_ws, float* __restrict__ m_ws, float* __restrict__ l_ws)
{
    __shared__ f16 sKT[64 * 72];        // [key_local][ci], stride 144 B
    __shared__ f16 sVT[64 * 72];        // [channel][key_local]
    __shared__ f16 sPS[4 * 32 * 72];    // per-wave P [query_local(32)][key(64)]
    __shared__ float sAL[4 * 32];       // per-wave alpha[query]

    const int t = threadIdx.x;
    const int L = t & 63, w = t >> 6;
    const int l5 = L >> 5, l31 = L & 31;
    const int qb = blockIdx.x >> 3, sp = blockIdx.x & 7;
    const int n0 = qb * 128;
    const int mbase = sp * SPLEN;
    f16* psw = (f16*)sPS + w * 32 * 72;
    float* alw = (float*)sAL + w * 32;

    // Q B-fragments (query = n0 + 32w + l31, ci chunks of 16)
    f16x8 qf[4];
    #pragma unroll
    for (int kc = 0; kc < 4; ++kc)
        qf[kc] = *(const f16x8*)(yq + (n0 + w * 32 + l31) * 64 + kc * 16 + l5 * 8);

    float mi = -1e30f, li = 0.f;        // per-lane query state (li = partial over l5 half)
    f32x16 acc[2];
    #pragma unroll
    for (int ct = 0; ct < 2; ++ct)
        #pragma unroll
        for (int r = 0; r < 16; ++r) acc[ct][r] = 0.f;

    for (int it = 0; it < ITERS; ++it) {
        const int m0 = mbase + it * 64;
        __syncthreads();
        #pragma unroll
        for (int rep = 0; rep < 2; ++rep) {
            int idx = t + rep * 256;
            int row = idx >> 3, ch = idx & 7;
            *(uint4*)&sKT[row * 72 + ch * 8] = *(const uint4*)&kt[(m0 + row) * 64 + ch * 8];
            *(uint4*)&sVT[row * 72 + ch * 8] = *(const uint4*)&vt[row * HW + m0 + ch * 8];
        }
        __syncthreads();

        // S^T: D[key32-tile][query]; lane: query=l31, keys kt2*32 + 8*(r>>2) + 4*l5 + (r&3)
        f32x16 st[2];
        #pragma unroll
        for (int kt2 = 0; kt2 < 2; ++kt2) {
            f32x16 d;
            #pragma unroll
            for (int r = 0; r < 16; ++r) d[r] = 0.f;
            #pragma unroll
            for (int kc = 0; kc < 4; ++kc) {
                f16x8 af = *(const f16x8*)&sKT[(kt2 * 32 + l31) * 72 + kc * 16 + l5 * 8];
                d = __builtin_amdgcn_mfma_f32_32x32x16_f16(af, qf[kc], d, 0, 0, 0);
            }
            st[kt2] = d;
        }
        // threshold mask to ZERO
        #pragma unroll
        for (int kt2 = 0; kt2 < 2; ++kt2)
            #pragma unroll
            for (int r = 0; r < 16; ++r)
                st[kt2][r] = (fabsf(st[kt2][r]) > 0.3f) ? st[kt2][r] : 0.f;

        // row max: 31 local + 1 shfl (partner l5 holds other half of this query's keys)
        float q8[8];
        #pragma unroll
        for (int kt2 = 0; kt2 < 2; ++kt2)
            #pragma unroll
            for (int rq = 0; rq < 4; ++rq)
                q8[kt2 * 4 + rq] = fmaxf(fmaxf(st[kt2][rq * 4 + 0], st[kt2][rq * 4 + 1]),
                                         fmaxf(st[kt2][rq * 4 + 2], st[kt2][rq * 4 + 3]));
        float mx = fmaxf(fmaxf(fmaxf(q8[0], q8[1]), fmaxf(q8[2], q8[3])),
                         fmaxf(fmaxf(q8[4], q8[5]), fmaxf(q8[6], q8[7])));
        mx = fmaxf(mx, __shfl_xor(mx, 32, 64));
        float mnew = fmaxf(mi, mx);
        float nL = mnew * LOG2E;
        float alpha = __builtin_amdgcn_exp2f(mi * LOG2E - nL);
        mi = mnew;

        // p = exp2(s*L2E - nL); immediate packed b64 P-writes; partial li
        float ls = 0.f;
        #pragma unroll
        for (int kt2 = 0; kt2 < 2; ++kt2)
            #pragma unroll
            for (int rq = 0; rq < 4; ++rq) {
                float p0 = __builtin_amdgcn_exp2f(fmaf(st[kt2][rq * 4 + 0], LOG2E, -nL));
                float p1 = __builtin_amdgcn_exp2f(fmaf(st[kt2][rq * 4 + 1], LOG2E, -nL));
                float p2 = __builtin_amdgcn_exp2f(fmaf(st[kt2][rq * 4 + 2], LOG2E, -nL));
                float p3 = __builtin_amdgcn_exp2f(fmaf(st[kt2][rq * 4 + 3], LOG2E, -nL));
                ls += (p0 + p1) + (p2 + p3);
                unsigned u0 = __builtin_bit_cast(unsigned int, __builtin_amdgcn_cvt_pkrtz(p0, p1));
                unsigned u1 = __builtin_bit_cast(unsigned int, __builtin_amdgcn_cvt_pkrtz(p2, p3));
                uint2 uv; uv.x = u0; uv.y = u1;
                *(uint2*)&psw[l31 * 72 + kt2 * 32 + rq * 8 + l5 * 4] = uv;
            }
        li = li * alpha + ls;

        // alpha redistribution (acc rows are reg-mapped queries): 1 write + 4 b128 reads
        if (l5 == 0) alw[l31] = alpha;
        f32x4 aj[4];
        #pragma unroll
        for (int rq = 0; rq < 4; ++rq)
            aj[rq] = *(const f32x4*)&alw[rq * 8 + l5 * 4];
        #pragma unroll
        for (int ct = 0; ct < 2; ++ct)
            #pragma unroll
            for (int r = 0; r < 16; ++r)
                acc[ct][r] *= aj[r >> 2][r & 3];

        // PV: A = P (4 k-chunks, reused over 2 c-tiles), B = V^T
        f16x8 pa[4];
        #pragma unroll
        for (int kc = 0; kc < 4; ++kc)
            pa[kc] = *(const f16x8*)&psw[l31 * 72 + kc * 16 + l5 * 8];
        #pragma unroll
        for (int ct = 0; ct < 2; ++ct)
            #pragma unroll
            for (int kc = 0; kc < 4; ++kc) {
                f16x8 vb = *(const f16x8*)&sVT[(ct * 32 + l31) * 72 + kc * 16 + l5 * 8];
                acc[ct] = __builtin_amdgcn_mfma_f32_32x32x16_f16(pa[kc], vb, acc[ct], 0, 0, 0);
            }
    }

    // finish row-sum (partner halves)
    float li_tot = li + __shfl_xor(li, 32, 64);

    // write partials: acc_ws[base*8192 + q_local*64 + c]
    const int base = blockIdx.x;
    #pragma unroll
    for (int ct = 0; ct < 2; ++ct)
        #pragma unroll
        for (int r = 0; r < 16; ++r) {
            int ql = w * 32 + (r & 3) + 8 * (r >> 2) + 4 * l5;
            int c  = ct * 32 + l31;
            acc_ws[base * 8192 + ql * 64 + c] = (f16)acc[ct][r];
        }
    if (l5 == 0) {
        m_ws[base * 128 + w * 32 + l31] = mi;    // unscaled units
        l_ws[base * 128 + w * 32 + l31] = li_tot;
    }
}

// ---------------- merge splits + residual + transpose; grid 576 (16-row tiles, 128-q blocks)
__global__ __launch_bounds__(256) void merge_kernel(
    const f16* __restrict__ acc_ws, const float* __restrict__ m_ws, const float* __restrict__ l_ws,
    const float* __restrict__ x, float* __restrict__ out)
{
    __shared__ float wsh[SPLITS * 16];
    __shared__ float att[64 * 17];
    const int b = blockIdx.x;            // 576 tiles of 16 query rows
    const int row0 = b * 16;
    const int qb = row0 >> 7;            // 16-row tile never crosses a 128-q block
    const int ql0 = row0 & 127;
    const int t = threadIdx.x;
    if (t < 16) {
        int ql = ql0 + t;
        float ms = -1e30f;
        float mv[SPLITS];
        #pragma unroll
        for (int sp = 0; sp < SPLITS; ++sp) {
            mv[sp] = m_ws[(qb * SPLITS + sp) * 128 + ql];
            ms = fmaxf(ms, mv[sp]);
        }
        float Lsum = 0.f, ev[SPLITS];
        #pragma unroll
        for (int sp = 0; sp < SPLITS; ++sp) {
            ev[sp] = __builtin_amdgcn_exp2f((mv[sp] - ms) * LOG2E);
            Lsum += l_ws[(qb * SPLITS + sp) * 128 + ql] * ev[sp];
        }
        float inv = 1.f / Lsum;
        #pragma unroll
        for (int sp = 0; sp < SPLITS; ++sp)
            wsh[sp * 16 + t] = ev[sp] * inv;
    }
    __syncthreads();
    for (int i = t; i < 1024; i += 256) {
        int rr = i >> 6, c = i & 63;         // c fast -> coalesced acc_ws reads
        float v = 0.f;
        #pragma unroll
        for (int sp = 0; sp < SPLITS; ++sp)
            v += (float)acc_ws[(qb * SPLITS + sp) * 8192 + (ql0 + rr) * 64 + c] * wsh[sp * 16 + rr];
        att[c * 17 + rr] = v;
    }
    __syncthreads();
    for (int i = t; i < 1024; i += 256) {
        int c = i >> 4, r = i & 15;
        int idx = c * HW + row0 + r;
        out[idx] = x[idx] + att[c * 17 + r];
    }
}

extern "C" void kernel_launch(void* const* d_in, const int* in_sizes, int n_in,
                              void* d_out, int out_size, void* d_ws, size_t ws_size,
                              hipStream_t stream)
{
    const float* x  = (const float*)d_in[0];
    const float* dW = (const float*)d_in[1];
    const float* db = (const float*)d_in[2];
    const float* cW = (const float*)d_in[3];
    const float* cb = (const float*)d_in[4];
    float* out = (float*)d_out;

    char* ws = (char*)d_ws;
    f16* kt     = (f16*)(ws);                        // 1,179,648 B
    f16* yq     = (f16*)(ws + 1179648);              // 1,179,648 B
    f16* vt     = (f16*)(ws + 2359296);              // 1,179,648 B
    f16* xt     = (f16*)(ws + 3538944);              // 1,280,000 B (xt[p][ci])
    f16* acc_ws = (f16*)(ws + 4818944);              // 9,437,184 B (576 blk * 8192)
    float* m_ws = (float*)(ws + 14256128);           //   294,912 B (576 * 128)
    float* l_ws = (float*)(ws + 14551040);           //   294,912 B
                                                     // total 14,845,952 B

    prepad_kernel<<<dim3(157), dim3(256), 0, stream>>>(x, xt);
    conv_mfma_kernel<<<dim3(576), dim3(256), 0, stream>>>(xt, dW, db, cW, cb, yq, kt, vt);
    attn_kernel<<<dim3(72 * SPLITS), dim3(256), 0, stream>>>(kt, vt, yq, acc_ws, m_ws, l_ws);
    merge_kernel<<<dim3(576), dim3(256), 0, stream>>>(acc_ws, m_ws, l_ws, x, out);
}

// Round 17
// 138.199 us; speedup vs baseline: 1.9373x; 1.0104x over previous
//
#include <hip/hip_runtime.h>
#include <hip/hip_bf16.h>

#define CC 64
#define HW 9216
#define IMG 96
#define SPLITS 8
#define SPLEN 1152            // 9216 / 8
#define ITERS 18              // 1152 / 64
#define LOG2E 1.44269504f

typedef _Float16 f16;
typedef __attribute__((ext_vector_type(8))) _Float16 f16x8;
typedef __attribute__((ext_vector_type(4))) _Float16 f16x4;
typedef __attribute__((ext_vector_type(4))) float f32x4;
typedef __attribute__((ext_vector_type(16))) float f32x16;

// ---------------- prepad + transpose: xt[p][ci] (p in 100x100 padded image, 64 f16 rows)
__global__ __launch_bounds__(256) void prepad_kernel(
    const float* __restrict__ x, f16* __restrict__ xt)
{
    __shared__ float tile[64][65];
    const int p0 = blockIdx.x * 64;              // grid 157 (157*64 = 10048 >= 10000)
    const int t = threadIdx.x;
    const int pl = t & 63;
    const int p = p0 + pl;
    int r = p / 100, c = p % 100;
    bool interior = (r >= 2) && (r < 98) && (c >= 2) && (c < 98);
    int img = (r - 2) * IMG + (c - 2);
    #pragma unroll
    for (int j = 0; j < 16; ++j) {
        int ci = j * 4 + (t >> 6);
        tile[pl][ci] = interior ? x[ci * HW + img] : 0.f;   // coalesced in p
    }
    __syncthreads();
    const int row16 = t >> 4, chunk = t & 15;
    #pragma unroll
    for (int j = 0; j < 4; ++j) {
        int row = j * 16 + row16;
        int pr = p0 + row;
        if (pr < 10000) {
            f16x4 hv = {(f16)tile[row][chunk * 4 + 0], (f16)tile[row][chunk * 4 + 1],
                        (f16)tile[row][chunk * 4 + 2], (f16)tile[row][chunk * 4 + 3]};
            *(f16x4*)&xt[pr * 64 + chunk * 4] = hv;          // coalesced 128B rows
        }
    }
}

// ---------------- MFMA conv: dilated 3x3 (9-tap GEMM over ci) + fused 1x1 (center tap)
__global__ __launch_bounds__(256) void conv_mfma_kernel(
    const f16* __restrict__ xt, const float* __restrict__ dW, const float* __restrict__ db,
    const float* __restrict__ cW, const float* __restrict__ cb,
    f16* __restrict__ yq, f16* __restrict__ kt, f16* __restrict__ vt)
{
    __shared__ f16 Wl[9 * 16 * 64];      // [tap][co][ci]  18 KB
    __shared__ f16 cWl[16 * 64];         // [co][ci]        2 KB

    const int b = blockIdx.x;            // 144 m-blocks * 4 co-groups
    const int mblk = b >> 2, cog = b & 3;
    const int co0 = cog * 16;
    const int t = threadIdx.x;

    // COALESCED flat read of dW (4 lines/wave-instr) + LDS-scattered b16 write
    #pragma unroll 4
    for (int j = 0; j < 36; ++j) {
        int d = j * 256 + t;
        float val = dW[co0 * 576 + d];       // lane-linear -> coalesced
        int co  = d / 576;                   // 0..15
        int r   = d - co * 576;              // 0..575
        int ci  = r / 9;
        int tap = r - ci * 9;
        Wl[tap * 1024 + co * 64 + ci] = (f16)val;
    }
    #pragma unroll
    for (int j = 0; j < 4; ++j) {
        int d = j * 256 + t;
        cWl[d] = (f16)cW[co0 * CC + d];      // already coalesced
    }
    __syncthreads();

    const int w = t >> 6, L = t & 63, g = L >> 4, c16 = L & 15;
    const int ms = mblk * 64 + w * 16;           // 16-aligned strip within one image row
    const int h = ms / IMG, wc = ms % IMG;
    const int pb = (h + 2) * 100 + (wc + 2) + c16;

    f16x8 Bf[9][2], Bv[2];
    #pragma unroll
    for (int tap = 0; tap < 9; ++tap)
        #pragma unroll
        for (int kc = 0; kc < 2; ++kc)
            Bf[tap][kc] = *(const f16x8*)&Wl[(tap * 16 + c16) * 64 + g * 8 + kc * 32];
    #pragma unroll
    for (int kc = 0; kc < 2; ++kc)
        Bv[kc] = *(const f16x8*)&cWl[c16 * 64 + g * 8 + kc * 32];

    f32x4 accY = (f32x4){0.f, 0.f, 0.f, 0.f};
    f32x4 accV = (f32x4){0.f, 0.f, 0.f, 0.f};

    #pragma unroll
    for (int tap = 0; tap < 9; ++tap) {
        int kh = tap / 3, kw = tap % 3;
        int toff = (2 * kh - 2) * 100 + (2 * kw - 2);
        const f16* ap = xt + (pb + toff) * 64;
        f16x8 A0 = *(const f16x8*)(ap + g * 8);
        f16x8 A1 = *(const f16x8*)(ap + g * 8 + 32);
        accY = __builtin_amdgcn_mfma_f32_16x16x32_f16(A0, Bf[tap][0], accY, 0, 0, 0);
        accY = __builtin_amdgcn_mfma_f32_16x16x32_f16(A1, Bf[tap][1], accY, 0, 0, 0);
        if (tap == 4) {
            accV = __builtin_amdgcn_mfma_f32_16x16x32_f16(A0, Bv[0], accV, 0, 0, 0);
            accV = __builtin_amdgcn_mfma_f32_16x16x32_f16(A1, Bv[1], accV, 0, 0, 0);
        }
    }

    const float dbv = db[co0 + c16], cbv = cb[co0 + c16];
    f16 hy[4];
    #pragma unroll
    for (int j = 0; j < 4; ++j) hy[j] = (f16)(accY[j] + dbv);
    *(f16x4*)&yq[(co0 + c16) * HW + ms + 4 * g] = (f16x4){hy[0], hy[1], hy[2], hy[3]};
    #pragma unroll
    for (int j = 0; j < 4; ++j)
        kt[(ms + 4 * g + j) * 64 + co0 + c16] = hy[j];
    #pragma unroll
    for (int j = 0; j < 4; ++j) {
        int m = ms + 4 * g + j;
        vt[(m & 63) * HW + (co0 + c16) * 144 + (m >> 6)] = (f16)(accV[j] + cbv);
    }
}

// ---------------- MFMA flash attention, 32x32x16 tiles (R16 kernel, proven 54 us)
__global__ __launch_bounds__(256, 3) void attn_kernel(
    const f16* __restrict__ kt, const f16* __restrict__ vt, const f16* __restrict__ yq,
    f16* __restrict__ acc_ws, float* __restrict__ m_ws, float* __restrict__ l_ws)
{
    __shared__ f16 sKT[64 * 72];        // [key_local][ci], stride 144 B
    __shared__ f16 sVT[64 * 72];        // [channel][key_local]
    __shared__ f16 sPS[4 * 32 * 72];    // per-wave P [query_local(32)][key(64)]
    __shared__ float sAL[4 * 32];       // per-wave alpha[query]

    const int t = threadIdx.x;
    const int L = t & 63, w = t >> 6;
    const int l5 = L >> 5, l31 = L & 31;
    const int qb = blockIdx.x >> 3, sp = blockIdx.x & 7;
    const int n0 = qb * 128;
    const int mbase = sp * SPLEN;
    f16* psw = (f16*)sPS + w * 32 * 72;
    float* alw = (float*)sAL + w * 32;

    // Q B-fragments (query = n0 + 32w + l31, ci chunks of 16)
    f16x8 qf[4];
    #pragma unroll
    for (int kc = 0; kc < 4; ++kc)
        qf[kc] = *(const f16x8*)(yq + (n0 + w * 32 + l31) * 64 + kc * 16 + l5 * 8);

    float mi = -1e30f, li = 0.f;        // per-lane query state (li = partial over l5 half)
    f32x16 acc[2];
    #pragma unroll
    for (int ct = 0; ct < 2; ++ct)
        #pragma unroll
        for (int r = 0; r < 16; ++r) acc[ct][r] = 0.f;

    for (int it = 0; it < ITERS; ++it) {
        const int m0 = mbase + it * 64;
        __syncthreads();
        #pragma unroll
        for (int rep = 0; rep < 2; ++rep) {
            int idx = t + rep * 256;
            int row = idx >> 3, ch = idx & 7;
            *(uint4*)&sKT[row * 72 + ch * 8] = *(const uint4*)&kt[(m0 + row) * 64 + ch * 8];
            *(uint4*)&sVT[row * 72 + ch * 8] = *(const uint4*)&vt[row * HW + m0 + ch * 8];
        }
        __syncthreads();

        // S^T: D[key32-tile][query]; lane: query=l31, keys kt2*32 + 8*(r>>2) + 4*l5 + (r&3)
        f32x16 st[2];
        #pragma unroll
        for (int kt2 = 0; kt2 < 2; ++kt2) {
            f32x16 d;
            #pragma unroll
            for (int r = 0; r < 16; ++r) d[r] = 0.f;
            #pragma unroll
            for (int kc = 0; kc < 4; ++kc) {
                f16x8 af = *(const f16x8*)&sKT[(kt2 * 32 + l31) * 72 + kc * 16 + l5 * 8];
                d = __builtin_amdgcn_mfma_f32_32x32x16_f16(af, qf[kc], d, 0, 0, 0);
            }
            st[kt2] = d;
        }
        // threshold mask to ZERO
        #pragma unroll
        for (int kt2 = 0; kt2 < 2; ++kt2)
            #pragma unroll
            for (int r = 0; r < 16; ++r)
                st[kt2][r] = (fabsf(st[kt2][r]) > 0.3f) ? st[kt2][r] : 0.f;

        // row max: 31 local + 1 shfl (partner l5 holds other half of this query's keys)
        float q8[8];
        #pragma unroll
        for (int kt2 = 0; kt2 < 2; ++kt2)
            #pragma unroll
            for (int rq = 0; rq < 4; ++rq)
                q8[kt2 * 4 + rq] = fmaxf(fmaxf(st[kt2][rq * 4 + 0], st[kt2][rq * 4 + 1]),
                                         fmaxf(st[kt2][rq * 4 + 2], st[kt2][rq * 4 + 3]));
        float mx = fmaxf(fmaxf(fmaxf(q8[0], q8[1]), fmaxf(q8[2], q8[3])),
                         fmaxf(fmaxf(q8[4], q8[5]), fmaxf(q8[6], q8[7])));
        mx = fmaxf(mx, __shfl_xor(mx, 32, 64));
        float mnew = fmaxf(mi, mx);
        float nL = mnew * LOG2E;
        float alpha = __builtin_amdgcn_exp2f(mi * LOG2E - nL);
        mi = mnew;

        // p = exp2(s*L2E - nL); immediate packed b64 P-writes; partial li
        float ls = 0.f;
        #pragma unroll
        for (int kt2 = 0; kt2 < 2; ++kt2)
            #pragma unroll
            for (int rq = 0; rq < 4; ++rq) {
                float p0 = __builtin_amdgcn_exp2f(fmaf(st[kt2][rq * 4 + 0], LOG2E, -nL));
                float p1 = __builtin_amdgcn_exp2f(fmaf(st[kt2][rq * 4 + 1], LOG2E, -nL));
                float p2 = __builtin_amdgcn_exp2f(fmaf(st[kt2][rq * 4 + 2], LOG2E, -nL));
                float p3 = __builtin_amdgcn_exp2f(fmaf(st[kt2][rq * 4 + 3], LOG2E, -nL));
                ls += (p0 + p1) + (p2 + p3);
                unsigned u0 = __builtin_bit_cast(unsigned int, __builtin_amdgcn_cvt_pkrtz(p0, p1));
                unsigned u1 = __builtin_bit_cast(unsigned int, __builtin_amdgcn_cvt_pkrtz(p2, p3));
                uint2 uv; uv.x = u0; uv.y = u1;
                *(uint2*)&psw[l31 * 72 + kt2 * 32 + rq * 8 + l5 * 4] = uv;
            }
        li = li * alpha + ls;

        // alpha redistribution (acc rows are reg-mapped queries): 1 write + 4 b128 reads
        if (l5 == 0) alw[l31] = alpha;
        f32x4 aj[4];
        #pragma unroll
        for (int rq = 0; rq < 4; ++rq)
            aj[rq] = *(const f32x4*)&alw[rq * 8 + l5 * 4];
        #pragma unroll
        for (int ct = 0; ct < 2; ++ct)
            #pragma unroll
            for (int r = 0; r < 16; ++r)
                acc[ct][r] *= aj[r >> 2][r & 3];

        // PV: A = P (4 k-chunks, reused over 2 c-tiles), B = V^T
        f16x8 pa[4];
        #pragma unroll
        for (int kc = 0; kc < 4; ++kc)
            pa[kc] = *(const f16x8*)&psw[l31 * 72 + kc * 16 + l5 * 8];
        #pragma unroll
        for (int ct = 0; ct < 2; ++ct)
            #pragma unroll
            for (int kc = 0; kc < 4; ++kc) {
                f16x8 vb = *(const f16x8*)&sVT[(ct * 32 + l31) * 72 + kc * 16 + l5 * 8];
                acc[ct] = __builtin_amdgcn_mfma_f32_32x32x16_f16(pa[kc], vb, acc[ct], 0, 0, 0);
            }
    }

    // finish row-sum (partner halves)
    float li_tot = li + __shfl_xor(li, 32, 64);

    // write partials: acc_ws[base*8192 + q_local*64 + c]
    const int base = blockIdx.x;
    #pragma unroll
    for (int ct = 0; ct < 2; ++ct)
        #pragma unroll
        for (int r = 0; r < 16; ++r) {
            int ql = w * 32 + (r & 3) + 8 * (r >> 2) + 4 * l5;
            int c  = ct * 32 + l31;
            acc_ws[base * 8192 + ql * 64 + c] = (f16)acc[ct][r];
        }
    if (l5 == 0) {
        m_ws[base * 128 + w * 32 + l31] = mi;    // unscaled units
        l_ws[base * 128 + w * 32 + l31] = li_tot;
    }
}

// ---------------- merge splits + residual + transpose; grid 576 (16-row tiles, 128-q blocks)
__global__ __launch_bounds__(256) void merge_kernel(
    const f16* __restrict__ acc_ws, const float* __restrict__ m_ws, const float* __restrict__ l_ws,
    const float* __restrict__ x, float* __restrict__ out)
{
    __shared__ float wsh[SPLITS * 16];
    __shared__ float att[64 * 17];
    const int b = blockIdx.x;            // 576 tiles of 16 query rows
    const int row0 = b * 16;
    const int qb = row0 >> 7;            // 16-row tile never crosses a 128-q block
    const int ql0 = row0 & 127;
    const int t = threadIdx.x;
    if (t < 16) {
        int ql = ql0 + t;
        float ms = -1e30f;
        float mv[SPLITS];
        #pragma unroll
        for (int sp = 0; sp < SPLITS; ++sp) {
            mv[sp] = m_ws[(qb * SPLITS + sp) * 128 + ql];
            ms = fmaxf(ms, mv[sp]);
        }
        float Lsum = 0.f, ev[SPLITS];
        #pragma unroll
        for (int sp = 0; sp < SPLITS; ++sp) {
            ev[sp] = __builtin_amdgcn_exp2f((mv[sp] - ms) * LOG2E);
            Lsum += l_ws[(qb * SPLITS + sp) * 128 + ql] * ev[sp];
        }
        float inv = 1.f / Lsum;
        #pragma unroll
        for (int sp = 0; sp < SPLITS; ++sp)
            wsh[sp * 16 + t] = ev[sp] * inv;
    }
    __syncthreads();
    for (int i = t; i < 1024; i += 256) {
        int rr = i >> 6, c = i & 63;         // c fast -> coalesced acc_ws reads
        float v = 0.f;
        #pragma unroll
        for (int sp = 0; sp < SPLITS; ++sp)
            v += (float)acc_ws[(qb * SPLITS + sp) * 8192 + (ql0 + rr) * 64 + c] * wsh[sp * 16 + rr];
        att[c * 17 + rr] = v;
    }
    __syncthreads();
    for (int i = t; i < 1024; i += 256) {
        int c = i >> 4, r = i & 15;
        int idx = c * HW + row0 + r;
        out[idx] = x[idx] + att[c * 17 + r];
    }
}

extern "C" void kernel_launch(void* const* d_in, const int* in_sizes, int n_in,
                              void* d_out, int out_size, void* d_ws, size_t ws_size,
                              hipStream_t stream)
{
    const float* x  = (const float*)d_in[0];
    const float* dW = (const float*)d_in[1];
    const float* db = (const float*)d_in[2];
    const float* cW = (const float*)d_in[3];
    const float* cb = (const float*)d_in[4];
    float* out = (float*)d_out;

    char* ws = (char*)d_ws;
    f16* kt     = (f16*)(ws);                        // 1,179,648 B
    f16* yq     = (f16*)(ws + 1179648);              // 1,179,648 B
    f16* vt     = (f16*)(ws + 2359296);              // 1,179,648 B
    f16* xt     = (f16*)(ws + 3538944);              // 1,280,000 B (xt[p][ci])
    f16* acc_ws = (f16*)(ws + 4818944);              // 9,437,184 B (576 blk * 8192)
    float* m_ws = (float*)(ws + 14256128);           //   294,912 B (576 * 128)
    float* l_ws = (float*)(ws + 14551040);           //   294,912 B
                                                     // total 14,845,952 B

    prepad_kernel<<<dim3(157), dim3(256), 0, stream>>>(x, xt);
    conv_mfma_kernel<<<dim3(576), dim3(256), 0, stream>>>(xt, dW, db, cW, cb, yq, kt, vt);
    attn_kernel<<<dim3(72 * SPLITS), dim3(256), 0, stream>>>(kt, vt, yq, acc_ws, m_ws, l_ws);
    merge_kernel<<<dim3(576), dim3(256), 0, stream>>>(acc_ws, m_ws, l_ws, x, out);
}